// Round 5
// baseline (184957.471 us; speedup 1.0000x reference)
//
#include <hip/hip_runtime.h>
#include <cmath>

constexpr int cB = 512, cT = 64, cD = 512, cH = 8, cDH = 64, cFF = 2048;
constexpr float cSCALE = 0.125f;  // DH^-0.5
constexpr unsigned cNBLK = 1024;

typedef short bfrag __attribute__((ext_vector_type(8)));   // 8 bf16 = 4 VGPRs
typedef float f32x4 __attribute__((ext_vector_type(4)));

__device__ __forceinline__ short f2bf(float x) {
  union { float f; unsigned u; } v{x};
  unsigned r = v.u + 0x7fff + ((v.u >> 16) & 1);
  return (short)(r >> 16);
}
__device__ __forceinline__ float bf2f(short s) {
  union { unsigned u; float f; } v;
  v.u = ((unsigned)(unsigned short)s) << 16;
  return v.f;
}
__device__ __forceinline__ float sigm(float z) { return 1.f / (1.f + __expf(-z)); }

// ---------------- hand-rolled grid barrier (monotonic counter) --------------
// All 1024 blocks are co-resident (__launch_bounds__(256,4) -> 4 blocks/CU x
// 256 CUs). Device-scope atomics + explicit agent fences for cross-XCD
// visibility of non-atomic data.
__device__ __forceinline__ void gridbar(unsigned* bar) {
  __syncthreads();
  if (threadIdx.x == 0) {
    __threadfence();  // agent-scope release (L2 writeback on gfx950)
    unsigned old = __hip_atomic_fetch_add(bar, 1u, __ATOMIC_ACQ_REL,
                                          __HIP_MEMORY_SCOPE_AGENT);
    unsigned need = (old / cNBLK + 1u) * cNBLK;
    while (__hip_atomic_load(bar, __ATOMIC_ACQUIRE,
                             __HIP_MEMORY_SCOPE_AGENT) < need) {
      __builtin_amdgcn_s_sleep(2);
    }
    __threadfence();  // agent-scope acquire (cache invalidate)
  }
  __syncthreads();
}

// ======================= standalone GEMMs (prep / epilogue) =================
enum GemmMode { MQ = 0, MWO, MFF1, MFF2 };

struct GemmArgs {
  const float *A, *A2, *sm, *sr, *g, *b;
  const short *WT, *WT2;   // hi / lo
  const float *bias, *extra;
  float *O;
  short *Os;
};

template<int MODE>
__device__ __forceinline__ float loadA(const GemmArgs& p, int r, int k) {
  if constexpr (MODE == MQ) {
    int t = r >> 9, bb = r & 511;
    float v = (t < cT) ? p.A[((size_t)bb * cT + t) * cD + k]
                       : p.A2[(size_t)bb * cD + k];
    return (v - p.sm[r]) * p.sr[r] * p.g[k] + p.b[k];
  } else if constexpr (MODE == MFF1) {
    return (p.A[(size_t)r * cD + k] - p.sm[r]) * p.sr[r] * p.g[k] + p.b[k];
  } else if constexpr (MODE == MFF2) {
    return p.A[(size_t)r * cFF + k];
  } else {  // MWO
    return p.A[(size_t)r * cD + k];
  }
}

template<int MODE>
__device__ __forceinline__ void epi(const GemmArgs& p, int r, int cn, float acc) {
  if constexpr (MODE == MQ) {
    p.Os[(size_t)r * cD + cn] = f2bf(acc);  // raw q, bf16 (l2n at consumer)
  } else if constexpr (MODE == MWO) {
    p.O[(size_t)r * cD + cn] = p.extra[(size_t)r * cD + cn] + acc + p.bias[cn];
  } else if constexpr (MODE == MFF1) {
    p.O[(size_t)r * cFF + cn] = fmaxf(acc + p.bias[cn], 0.f);
  } else {  // MFF2
    p.O[(size_t)r * cD + cn] = p.extra[(size_t)r * cD + cn] + acc + p.bias[cn];
  }
}

// single-precision bf16 MFMA GEMM (q_all — matches R2 numerics)
template<int MODE, int LDW>
__global__ __launch_bounds__(256) void mgemm(GemmArgs p, int K) {
  __shared__ short As[64][32];
  __shared__ short Bs[64][32];
  const int tid = threadIdx.x;
  const int lane = tid & 63, wid = tid >> 6;
  const int wm = wid & 1, wn = wid >> 1;
  const int l15 = lane & 15, qd = lane >> 4;
  const int row0 = blockIdx.x * 64;
  const int n0 = blockIdx.y * 64;

  f32x4 acc[2][2] = {};
  const int sm = tid >> 2;
  const int sk = (tid & 3) * 8;

  for (int k0 = 0; k0 < K; k0 += 32) {
    {
      short tmp[8];
#pragma unroll
      for (int j = 0; j < 8; ++j)
        tmp[j] = f2bf(loadA<MODE>(p, row0 + sm, k0 + sk + j));
      *((bfrag*)&As[sm][0] + (sk >> 3)) = *(bfrag*)tmp;
    }
    *((bfrag*)&Bs[sm][0] + (sk >> 3)) =
        *(const bfrag*)(p.WT + (size_t)(n0 + sm) * LDW + k0 + sk);
    __syncthreads();
    bfrag a0 = *((bfrag*)&As[wm * 32 + l15][0] + qd);
    bfrag a1 = *((bfrag*)&As[wm * 32 + 16 + l15][0] + qd);
    bfrag b0 = *((bfrag*)&Bs[wn * 32 + l15][0] + qd);
    bfrag b1 = *((bfrag*)&Bs[wn * 32 + 16 + l15][0] + qd);
    acc[0][0] = __builtin_amdgcn_mfma_f32_16x16x32_bf16(a0, b0, acc[0][0], 0, 0, 0);
    acc[0][1] = __builtin_amdgcn_mfma_f32_16x16x32_bf16(a0, b1, acc[0][1], 0, 0, 0);
    acc[1][0] = __builtin_amdgcn_mfma_f32_16x16x32_bf16(a1, b0, acc[1][0], 0, 0, 0);
    acc[1][1] = __builtin_amdgcn_mfma_f32_16x16x32_bf16(a1, b1, acc[1][1], 0, 0, 0);
    __syncthreads();
  }

#pragma unroll
  for (int fm = 0; fm < 2; ++fm)
#pragma unroll
    for (int fn = 0; fn < 2; ++fn)
#pragma unroll
      for (int rg = 0; rg < 4; ++rg)
        epi<MODE>(p, row0 + wm * 32 + fm * 16 + qd * 4 + rg,
                  n0 + wn * 32 + fn * 16 + l15, acc[fm][fn][rg]);
}

// split-precision GEMM (post-scan layers)
template<int MODE, int LDW>
__global__ __launch_bounds__(256) void pgemm(GemmArgs p, int K) {
  __shared__ short Ah[64][32], Al[64][32];
  __shared__ short Bh[64][32], Bl[64][32];
  const int tid = threadIdx.x;
  const int lane = tid & 63, wid = tid >> 6;
  const int wm = wid & 1, wn = wid >> 1;
  const int l15 = lane & 15, qd = lane >> 4;
  const int row0 = blockIdx.x * 64;
  const int n0 = blockIdx.y * 64;

  f32x4 acc[2][2] = {};
  const int sm = tid >> 2;
  const int sk = (tid & 3) * 8;

  for (int k0 = 0; k0 < K; k0 += 32) {
    {
      short th[8], tl[8];
#pragma unroll
      for (int j = 0; j < 8; ++j) {
        float a = loadA<MODE>(p, row0 + sm, k0 + sk + j);
        short h = f2bf(a);
        th[j] = h;
        tl[j] = f2bf(a - bf2f(h));
      }
      *((bfrag*)&Ah[sm][0] + (sk >> 3)) = *(bfrag*)th;
      *((bfrag*)&Al[sm][0] + (sk >> 3)) = *(bfrag*)tl;
    }
    *((bfrag*)&Bh[sm][0] + (sk >> 3)) =
        *(const bfrag*)(p.WT + (size_t)(n0 + sm) * LDW + k0 + sk);
    *((bfrag*)&Bl[sm][0] + (sk >> 3)) =
        *(const bfrag*)(p.WT2 + (size_t)(n0 + sm) * LDW + k0 + sk);
    __syncthreads();
#pragma unroll
    for (int fm = 0; fm < 2; ++fm) {
      bfrag ah = *((bfrag*)&Ah[wm * 32 + fm * 16 + l15][0] + qd);
      bfrag al = *((bfrag*)&Al[wm * 32 + fm * 16 + l15][0] + qd);
#pragma unroll
      for (int fn = 0; fn < 2; ++fn) {
        bfrag bh = *((bfrag*)&Bh[wn * 32 + fn * 16 + l15][0] + qd);
        bfrag bl = *((bfrag*)&Bl[wn * 32 + fn * 16 + l15][0] + qd);
        acc[fm][fn] = __builtin_amdgcn_mfma_f32_16x16x32_bf16(al, bh, acc[fm][fn], 0, 0, 0);
        acc[fm][fn] = __builtin_amdgcn_mfma_f32_16x16x32_bf16(ah, bl, acc[fm][fn], 0, 0, 0);
        acc[fm][fn] = __builtin_amdgcn_mfma_f32_16x16x32_bf16(ah, bh, acc[fm][fn], 0, 0, 0);
      }
    }
    __syncthreads();
  }

#pragma unroll
  for (int fm = 0; fm < 2; ++fm)
#pragma unroll
    for (int fn = 0; fn < 2; ++fn)
#pragma unroll
      for (int rg = 0; rg < 4; ++rg)
        epi<MODE>(p, row0 + wm * 32 + fm * 16 + qd * 4 + rg,
                  n0 + wn * 32 + fn * 16 + l15, acc[fm][fn][rg]);
}

// ======================= weight transpose + bf16 ============================
__global__ __launch_bounds__(256) void tconv(const float* __restrict__ W,
                                             short* __restrict__ WT, int K, int N) {
  __shared__ float tile[32][33];
  int k0 = blockIdx.x * 32, n0 = blockIdx.y * 32;
  int tx = threadIdx.x & 31, ty = threadIdx.x >> 5;
#pragma unroll
  for (int j = 0; j < 32; j += 8) {
    int k = k0 + ty + j, n = n0 + tx;
    tile[ty + j][tx] = (k < K && n < N) ? W[(size_t)k * N + n] : 0.f;
  }
  __syncthreads();
#pragma unroll
  for (int j = 0; j < 32; j += 8) {
    int n = n0 + ty + j, k = k0 + tx;
    if (n < N && k < K) WT[(size_t)n * K + k] = f2bf(tile[tx][ty + j]);
  }
}

__global__ __launch_bounds__(256) void tconv2(const float* __restrict__ W,
                                              short* __restrict__ WTh,
                                              short* __restrict__ WTl, int K, int N) {
  __shared__ float tile[32][33];
  int k0 = blockIdx.x * 32, n0 = blockIdx.y * 32;
  int tx = threadIdx.x & 31, ty = threadIdx.x >> 5;
#pragma unroll
  for (int j = 0; j < 32; j += 8) {
    int k = k0 + ty + j, n = n0 + tx;
    tile[ty + j][tx] = (k < K && n < N) ? W[(size_t)k * N + n] : 0.f;
  }
  __syncthreads();
#pragma unroll
  for (int j = 0; j < 32; j += 8) {
    int n = n0 + ty + j, k = k0 + tx;
    if (n < N && k < K) {
      float v = tile[tx][ty + j];
      short h = f2bf(v);
      WTh[(size_t)n * K + k] = h;
      WTl[(size_t)n * K + k] = f2bf(v - bf2f(h));
    }
  }
}

// ======================= LN stats + us_norm =================================
__global__ __launch_bounds__(256) void ln_stats_k(
    const float* __restrict__ item_seq, const float* __restrict__ last_item,
    const float* __restrict__ user, const float* __restrict__ n1g,
    const float* __restrict__ n1b, float* __restrict__ lnm,
    float* __restrict__ lnr, float* __restrict__ us_norm) {
  const int lane = threadIdx.x & 63;
  const int w = blockIdx.x * 4 + (threadIdx.x >> 6);
  const float* src;
  int cls, bi = 0;
  if (w < cT * cB) {
    int t = w >> 9, bb = w & 511;
    src = item_seq + ((size_t)bb * cT + t) * cD;
    cls = 0;
  } else if (w < cT * cB + cB) {
    bi = w - cT * cB;
    src = last_item + (size_t)bi * cD;
    cls = 1;
  } else {
    bi = w - cT * cB - cB;
    src = user + (size_t)bi * cD;
    cls = 2;
  }
  float x[8], s = 0.f, ss = 0.f;
#pragma unroll
  for (int i = 0; i < 8; ++i) {
    float v = src[lane + i * 64];
    x[i] = v; s += v; ss += v * v;
  }
#pragma unroll
  for (int o = 32; o >= 1; o >>= 1) { s += __shfl_xor(s, o); ss += __shfl_xor(ss, o); }
  float m = s * (1.f / cD);
  float rstd = rsqrtf(ss * (1.f / cD) - m * m + 1e-5f);
  if (cls == 0) {
    if (lane == 0) { lnm[w] = m; lnr[w] = rstd; }
  } else if (cls == 1) {
    if (lane == 0) { lnm[cT * cB + bi] = m; lnr[cT * cB + bi] = rstd; }
  } else {
#pragma unroll
    for (int i = 0; i < 8; ++i) {
      int d = lane + i * 64;
      us_norm[(size_t)bi * cD + d] = (x[i] - m) * rstd * n1g[d] + n1b[d];
    }
  }
}

// ======================= per-row stats ======================================
__global__ __launch_bounds__(256) void row_stats_k(const float* __restrict__ X,
                                                   float* __restrict__ M,
                                                   float* __restrict__ R) {
  const int lane = threadIdx.x & 63;
  const int w = blockIdx.x * 4 + (threadIdx.x >> 6);
  float s = 0.f, ss = 0.f;
#pragma unroll
  for (int i = 0; i < 8; ++i) {
    float v = X[(size_t)w * cD + lane + i * 64];
    s += v; ss += v * v;
  }
#pragma unroll
  for (int o = 32; o >= 1; o >>= 1) { s += __shfl_xor(s, o); ss += __shfl_xor(ss, o); }
  if (lane == 0) {
    float m = s * (1.f / cD);
    M[w] = m;
    R[w] = rsqrtf(ss * (1.f / cD) - m * m + 1e-5f);
  }
}

// ======================= cooperative-style scan kernel ======================
struct ScanParams {
  const float *item_seq, *init_state;
  const float *lnm, *lnr, *n1g, *n1b, *us_norm;
  const float *mcb1, *mcg, *mcbt, *mcb2, *ba, *be;
  const short *wt_m1, *wt_m1l, *wt_m2, *wt_m2l, *wt_kvae, *wt_kvael, *q_all;
  float *mem_ctx, *r_buf, *mo_buf;
  float *k_raw, *v_buf, *alpha_b, *eta_b, *state;
  unsigned *bar;
};

template<int PH>
__device__ __forceinline__ float ldA(const ScanParams& p, int t, int r, int k,
                                     const float* rmL, const float* rrL) {
  if constexpr (PH == 1) {  // [us_norm | mem_ctx]
    return (k < cD) ? p.us_norm[(size_t)r * cD + k]
                    : p.mem_ctx[(size_t)r * cD + (k - cD)];
  } else if constexpr (PH == 3) {  // relu(LN(r_buf)) with LDS stats
    float v = (p.r_buf[(size_t)r * cD + k] - rmL[r & 63]) * rrL[r & 63] *
                  p.mcg[k] + p.mcbt[k];
    return fmaxf(v, 0.f);
  } else {  // PH == 4: mod = i_norm*(1+tanh(gamma)) + beta
    float inm = (p.item_seq[((size_t)r * cT + t) * cD + k] - p.lnm[t * cB + r]) *
                    p.lnr[t * cB + r] * p.n1g[k] + p.n1b[k];
    float gam = p.mo_buf[(size_t)r * 1040 + k];
    float bet = p.mo_buf[(size_t)r * 1040 + 512 + k];
    return inm * (1.f + tanhf(gam)) + bet;
  }
}

// split-precision scan GEMM phase: A,W = bf16 hi+lo, 3 MFMAs per frag
template<int PH, int K>
__device__ void gemm_phase(const ScanParams& p, int t, int row0, int n0,
                           short (*Ah)[32], short (*Al)[32],
                           short (*Bh)[32], short (*Bl)[32],
                           const float* rmL, const float* rrL) {
  const int tid = threadIdx.x;
  const int lane = tid & 63, wid = tid >> 6;
  const int wm = wid & 1, wn = wid >> 1;
  const int l15 = lane & 15, qd = lane >> 4;

  f32x4 acc[2][2] = {};
  const int sm = tid >> 2;
  const int sk = (tid & 3) * 8;

  for (int k0 = 0; k0 < K; k0 += 32) {
    {
      short th[8], tl[8];
#pragma unroll
      for (int j = 0; j < 8; ++j) {
        float a = ldA<PH>(p, t, row0 + sm, k0 + sk + j, rmL, rrL);
        short h = f2bf(a);
        th[j] = h;
        tl[j] = f2bf(a - bf2f(h));
      }
      *((bfrag*)&Ah[sm][0] + (sk >> 3)) = *(bfrag*)th;
      *((bfrag*)&Al[sm][0] + (sk >> 3)) = *(bfrag*)tl;
    }
    {
      bfrag wh = {}, wl = {};
      if (PH == 1) {
        wh = *(const bfrag*)(p.wt_m1 + (size_t)(n0 + sm) * 1024 + k0 + sk);
        wl = *(const bfrag*)(p.wt_m1l + (size_t)(n0 + sm) * 1024 + k0 + sk);
      } else if (n0 + sm < 1040) {
        const short* wth = (PH == 3) ? p.wt_m2 : p.wt_kvae;
        const short* wtl = (PH == 3) ? p.wt_m2l : p.wt_kvael;
        wh = *(const bfrag*)(wth + (size_t)(n0 + sm) * 512 + k0 + sk);
        wl = *(const bfrag*)(wtl + (size_t)(n0 + sm) * 512 + k0 + sk);
      }
      *((bfrag*)&Bh[sm][0] + (sk >> 3)) = wh;
      *((bfrag*)&Bl[sm][0] + (sk >> 3)) = wl;
    }
    __syncthreads();
#pragma unroll
    for (int fm = 0; fm < 2; ++fm) {
      bfrag ah = *((bfrag*)&Ah[wm * 32 + fm * 16 + l15][0] + qd);
      bfrag al = *((bfrag*)&Al[wm * 32 + fm * 16 + l15][0] + qd);
#pragma unroll
      for (int fn = 0; fn < 2; ++fn) {
        bfrag bh = *((bfrag*)&Bh[wn * 32 + fn * 16 + l15][0] + qd);
        bfrag bl = *((bfrag*)&Bl[wn * 32 + fn * 16 + l15][0] + qd);
        acc[fm][fn] = __builtin_amdgcn_mfma_f32_16x16x32_bf16(al, bh, acc[fm][fn], 0, 0, 0);
        acc[fm][fn] = __builtin_amdgcn_mfma_f32_16x16x32_bf16(ah, bl, acc[fm][fn], 0, 0, 0);
        acc[fm][fn] = __builtin_amdgcn_mfma_f32_16x16x32_bf16(ah, bh, acc[fm][fn], 0, 0, 0);
      }
    }
    __syncthreads();
  }

#pragma unroll
  for (int fm = 0; fm < 2; ++fm)
#pragma unroll
    for (int fn = 0; fn < 2; ++fn)
#pragma unroll
      for (int rg = 0; rg < 4; ++rg) {
        int r = row0 + wm * 32 + fm * 16 + qd * 4 + rg;
        int cn = n0 + wn * 32 + fn * 16 + l15;
        float a = acc[fm][fn][rg];
        if constexpr (PH == 1) {
          p.r_buf[(size_t)r * cD + cn] = a + p.mcb1[cn];
        } else if constexpr (PH == 3) {
          if (cn < 1040) p.mo_buf[(size_t)r * 1040 + cn] = a + p.mcb2[cn];
        } else {  // PH == 4
          if (cn < 512) {
            p.k_raw[(size_t)r * cD + cn] = a;
          } else if (cn < 1024) {
            p.v_buf[(size_t)r * cD + (cn - 512)] = a;
          } else if (cn < 1032) {
            int h = cn - 1024;
            p.alpha_b[r * cH + h] = sigm(a + p.ba[h] + p.mo_buf[(size_t)r * 1040 + 1024 + h]);
          } else if (cn < 1040) {
            int h = cn - 1032;
            p.eta_b[r * cH + h] =
                cSCALE * sigm(a + p.be[h] + p.mo_buf[(size_t)r * 1040 + 1032 + h]);
          }
        }
      }
}

template<bool UPD>
__device__ void state_phase(const ScanParams& p, const float* __restrict__ Sin,
                            int qslot, float (*skq)[4][64]) {
  const int lane = threadIdx.x & 63;
  const int wi = threadIdx.x >> 6;
  const int w = blockIdx.x * 4 + wi;
  const int b = w >> 3, h = w & 7;

  float q = bf2f(p.q_all[(size_t)qslot * cB * cD + (size_t)b * cD + h * cDH + lane]);
  float qs = q * q;
#pragma unroll
  for (int o = 32; o >= 1; o >>= 1) qs += __shfl_xor(qs, o);
  skq[0][wi][lane] = q / fmaxf(sqrtf(qs), 1e-12f);

  if constexpr (UPD) {
    float kv = p.k_raw[(size_t)b * cD + h * cDH + lane];
    float ks = kv * kv;
#pragma unroll
    for (int o = 32; o >= 1; o >>= 1) ks += __shfl_xor(ks, o);
    skq[1][wi][lane] = kv / fmaxf(sqrtf(ks), 1e-12f);
  }

  float S[64];
  const float* sp = Sin + ((size_t)w * cDH + lane) * cDH;
#pragma unroll
  for (int j = 0; j < 64; j += 4) {
    float4 t4 = *(const float4*)(sp + j);
    S[j] = t4.x; S[j + 1] = t4.y; S[j + 2] = t4.z; S[j + 3] = t4.w;
  }

  float mem = 0.f;
  if constexpr (UPD) {
    float vv = p.v_buf[(size_t)b * cD + h * cDH + lane];
    float a = p.alpha_b[b * cH + h];
    float e = p.eta_b[b * cH + h];
    float pred = 0.f;
#pragma unroll
    for (int j = 0; j < 64; ++j) pred += S[j] * skq[1][wi][j];
    float f = e * (vv - pred);
    float oma = 1.f - a;
#pragma unroll
    for (int j = 0; j < 64; ++j) {
      S[j] = oma * S[j] + f * skq[1][wi][j];
      mem += S[j] * skq[0][wi][j];
    }
    float* op = p.state + ((size_t)w * cDH + lane) * cDH;
#pragma unroll
    for (int j = 0; j < 64; j += 4) {
      float4 t4 = make_float4(S[j], S[j + 1], S[j + 2], S[j + 3]);
      *(float4*)(op + j) = t4;
    }
  } else {
#pragma unroll
    for (int j = 0; j < 64; ++j) mem += S[j] * skq[0][wi][j];
  }
  p.mem_ctx[(size_t)b * cD + h * cDH + lane] = mem;
}

__global__ __launch_bounds__(256, 4) void scan_k(ScanParams p) {
  __shared__ short Ah[64][32], Al[64][32];
  __shared__ short Bh[64][32], Bl[64][32];
  __shared__ float skq[2][4][64];
  __shared__ float rmL[64], rrL[64];
  const int bid = blockIdx.x;

  // mem_ctx_0 = read(init_state, q_0)
  state_phase<false>(p, p.init_state, 0, skq);
  gridbar(p.bar);

  for (int t = 0; t < cT; ++t) {
    if (bid < 64)  // P1: meta1, full K=1024
      gemm_phase<1, 1024>(p, t, (bid >> 3) * 64, (bid & 7) * 64,
                          Ah, Al, Bh, Bl, nullptr, nullptr);
    gridbar(p.bar);
    if (bid < 136) {  // P3: meta2 + in-block LN stats of its 64 rows
      int row0 = (bid & 7) * 64;
      int lane = threadIdx.x & 63, wid = threadIdx.x >> 6;
      for (int rr2 = 0; rr2 < 16; ++rr2) {
        int row = row0 + wid * 16 + rr2;
        float s = 0.f, ss = 0.f;
#pragma unroll
        for (int i = 0; i < 8; ++i) {
          float v = p.r_buf[(size_t)row * cD + lane + i * 64];
          s += v; ss += v * v;
        }
#pragma unroll
        for (int o = 32; o >= 1; o >>= 1) { s += __shfl_xor(s, o); ss += __shfl_xor(ss, o); }
        if (lane == 0) {
          float m = s * (1.f / cD);
          rmL[wid * 16 + rr2] = m;
          rrL[wid * 16 + rr2] = rsqrtf(ss * (1.f / cD) - m * m + 1e-5f);
        }
      }
      __syncthreads();
      gemm_phase<3, 512>(p, t, row0, (bid >> 3) * 64, Ah, Al, Bh, Bl, rmL, rrL);
    }
    gridbar(p.bar);
    if (bid < 136)  // P4: kvae (mod fused into A-load)
      gemm_phase<4, 512>(p, t, (bid & 7) * 64, (bid >> 3) * 64,
                         Ah, Al, Bh, Bl, nullptr, nullptr);
    gridbar(p.bar);
    // P5: state update + read with q_{t+1}
    state_phase<true>(p, (t == 0) ? p.init_state : p.state, t + 1, skq);
    gridbar(p.bar);
  }
}

// ======================= host launch ========================================
extern "C" void kernel_launch(void* const* d_in, const int* in_sizes, int n_in,
                              void* d_out, int out_size, void* d_ws, size_t ws_size,
                              hipStream_t stream) {
  (void)in_sizes; (void)n_in; (void)out_size;
  const float* item_seq   = (const float*)d_in[0];
  const float* user_stat  = (const float*)d_in[1];
  const float* last_item  = (const float*)d_in[2];
  const float* init_state = (const float*)d_in[3];
  const float* Wq  = (const float*)d_in[4];
  const float* Wk  = (const float*)d_in[5];
  const float* Wv  = (const float*)d_in[6];
  const float* Wa  = (const float*)d_in[7];
  const float* ba  = (const float*)d_in[8];
  const float* We  = (const float*)d_in[9];
  const float* be  = (const float*)d_in[10];
  const float* mcW1 = (const float*)d_in[11];
  const float* mcb1 = (const float*)d_in[12];
  const float* mcg  = (const float*)d_in[13];
  const float* mcbt = (const float*)d_in[14];
  const float* mcW2 = (const float*)d_in[15];
  const float* mcb2 = (const float*)d_in[16];
  const float* Wo  = (const float*)d_in[17];
  const float* bo  = (const float*)d_in[18];
  const float* W1  = (const float*)d_in[19];
  const float* b1  = (const float*)d_in[20];
  const float* W2  = (const float*)d_in[21];
  const float* b2  = (const float*)d_in[22];
  const float* n1g = (const float*)d_in[23];
  const float* n1b = (const float*)d_in[24];
  const float* n2g = (const float*)d_in[25];
  const float* n2b = (const float*)d_in[26];

  float* ws = (float*)d_ws;
  size_t off = 0;
  auto alloc = [&](size_t n) { float* p = ws + off; off += n; return p; };
  auto salloc = [&](size_t n) { return (short*)alloc((n + 1) / 2); };

  unsigned* bar  = (unsigned*)alloc(16);  // 64B, zeroed below
  short* q_all   = salloc((size_t)(cT + 1) * cB * cD);
  float* state   = alloc((size_t)cB * cH * cDH * cDH);
  float* lnm     = alloc((size_t)(cT + 1) * cB);
  float* lnr     = alloc((size_t)(cT + 1) * cB);
  float* us_norm = alloc((size_t)cB * cD);
  float* mem_ctx = alloc((size_t)cB * cD);
  float* r_buf   = alloc((size_t)cB * cD);
  float* mo_buf  = alloc((size_t)cB * 1040);
  float* k_raw   = alloc((size_t)cB * cD);
  float* v_buf   = alloc((size_t)cB * cD);
  float* alpha_b = alloc((size_t)cB * cH);
  float* eta_b   = alloc((size_t)cB * cH);
  float* x_buf   = alloc((size_t)cB * cD);
  float* xm      = alloc(cB);
  float* xr      = alloc(cB);
  float* u_buf   = alloc((size_t)cB * cFF);
  short* wt_q    = salloc((size_t)512 * 512);
  short* wt_m1   = salloc((size_t)512 * 1024);
  short* wt_m1l  = salloc((size_t)512 * 1024);
  short* wt_m2   = salloc((size_t)1040 * 512);
  short* wt_m2l  = salloc((size_t)1040 * 512);
  short* wt_kvae = salloc((size_t)1040 * 512);
  short* wt_kvael= salloc((size_t)1040 * 512);
  short* wt_o    = salloc((size_t)512 * 512);
  short* wt_o_l  = salloc((size_t)512 * 512);
  short* wt_1    = salloc((size_t)2048 * 512);
  short* wt_1_l  = salloc((size_t)2048 * 512);
  short* wt_2    = salloc((size_t)512 * 2048);
  short* wt_2_l  = salloc((size_t)512 * 2048);
  if (ws_size < off * sizeof(float)) return;

  hipMemsetAsync(bar, 0, 64, stream);  // zero the grid barrier counter

  // --- prep ---
  tconv<<<dim3(16, 16), 256, 0, stream>>>(Wq, wt_q, 512, 512);
  tconv2<<<dim3(32, 16), 256, 0, stream>>>(mcW1, wt_m1, wt_m1l, 1024, 512);
  tconv2<<<dim3(16, 33), 256, 0, stream>>>(mcW2, wt_m2, wt_m2l, 512, 1040);
  tconv2<<<dim3(16, 16), 256, 0, stream>>>(Wk, wt_kvae, wt_kvael, 512, 512);
  tconv2<<<dim3(16, 16), 256, 0, stream>>>(Wv, wt_kvae + (size_t)512 * 512,
                                           wt_kvael + (size_t)512 * 512, 512, 512);
  tconv2<<<dim3(16, 1), 256, 0, stream>>>(Wa, wt_kvae + (size_t)1024 * 512,
                                          wt_kvael + (size_t)1024 * 512, 512, 8);
  tconv2<<<dim3(16, 1), 256, 0, stream>>>(We, wt_kvae + (size_t)1032 * 512,
                                          wt_kvael + (size_t)1032 * 512, 512, 8);
  tconv2<<<dim3(16, 16), 256, 0, stream>>>(Wo, wt_o, wt_o_l, 512, 512);
  tconv2<<<dim3(16, 64), 256, 0, stream>>>(W1, wt_1, wt_1_l, 512, 2048);
  tconv2<<<dim3(64, 16), 256, 0, stream>>>(W2, wt_2, wt_2_l, 2048, 512);

  ln_stats_k<<<(cT * cB + 2 * cB) / 4, 256, 0, stream>>>(
      item_seq, last_item, user_stat, n1g, n1b, lnm, lnr, us_norm);

  {  // q_all for all 65 slots (bf16 out)
    GemmArgs p{}; p.A = item_seq; p.A2 = last_item; p.sm = lnm; p.sr = lnr;
    p.g = n1g; p.b = n1b; p.WT = wt_q; p.Os = q_all;
    mgemm<MQ, 512><<<dim3(520, 8), 256, 0, stream>>>(p, 512);
  }

  {  // --- the whole 64-step scan, one kernel with custom grid barrier ---
    ScanParams sp{};
    sp.item_seq = item_seq; sp.init_state = init_state;
    sp.lnm = lnm; sp.lnr = lnr; sp.n1g = n1g; sp.n1b = n1b; sp.us_norm = us_norm;
    sp.mcb1 = mcb1; sp.mcg = mcg; sp.mcbt = mcbt; sp.mcb2 = mcb2;
    sp.ba = ba; sp.be = be;
    sp.wt_m1 = wt_m1; sp.wt_m1l = wt_m1l; sp.wt_m2 = wt_m2; sp.wt_m2l = wt_m2l;
    sp.wt_kvae = wt_kvae; sp.wt_kvael = wt_kvael; sp.q_all = q_all;
    sp.mem_ctx = mem_ctx; sp.r_buf = r_buf; sp.mo_buf = mo_buf;
    sp.k_raw = k_raw; sp.v_buf = v_buf;
    sp.alpha_b = alpha_b; sp.eta_b = eta_b; sp.state = state;
    sp.bar = bar;
    scan_k<<<dim3(cNBLK), dim3(256), 0, stream>>>(sp);
  }

  {  // x = user + mem_ctx @ Wo + bo  (split precision)
    GemmArgs p{}; p.A = mem_ctx; p.WT = wt_o; p.WT2 = wt_o_l;
    p.bias = bo; p.extra = user_stat; p.O = x_buf;
    pgemm<MWO, 512><<<dim3(8, 8), 256, 0, stream>>>(p, 512);
  }
  row_stats_k<<<cB / 4, 256, 0, stream>>>(x_buf, xm, xr);
  {  // u = relu(LN(x) @ W1 + b1)  (split precision)
    GemmArgs p{}; p.A = x_buf; p.sm = xm; p.sr = xr; p.g = n2g; p.b = n2b;
    p.WT = wt_1; p.WT2 = wt_1_l; p.bias = b1; p.O = u_buf;
    pgemm<MFF1, 512><<<dim3(8, 32), 256, 0, stream>>>(p, 512);
  }
  {  // out = x + u @ W2 + b2  (split precision)
    GemmArgs p{}; p.A = u_buf; p.WT = wt_2; p.WT2 = wt_2_l;
    p.bias = b2; p.extra = x_buf; p.O = (float*)d_out;
    pgemm<MFF2, 2048><<<dim3(8, 8), 256, 0, stream>>>(p, 2048);
  }
}

// Round 6
// 35804.993 us; speedup vs baseline: 5.1657x; 5.1657x over previous
//
#include <hip/hip_runtime.h>
#include <cmath>

constexpr int cB = 512, cT = 64, cD = 512, cH = 8, cDH = 64, cFF = 2048;
constexpr float cSCALE = 0.125f;  // DH^-0.5
constexpr unsigned cNBLK = 1024;

typedef short bfrag __attribute__((ext_vector_type(8)));   // 8 bf16 = 4 VGPRs
typedef float f32x4 __attribute__((ext_vector_type(4)));

__device__ __forceinline__ short f2bf(float x) {
  union { float f; unsigned u; } v{x};
  unsigned r = v.u + 0x7fff + ((v.u >> 16) & 1);
  return (short)(r >> 16);
}
__device__ __forceinline__ float bf2f(short s) {
  union { unsigned u; float f; } v;
  v.u = ((unsigned)(unsigned short)s) << 16;
  return v.f;
}
__device__ __forceinline__ float sigm(float z) { return 1.f / (1.f + __expf(-z)); }

// ---------------- grid barrier (monotonic counter) --------------------------
// KEY FIX vs R5: the RMW and the spin-poll are RELAXED. Agent-scope atomics
// execute at the device coherence point, so a relaxed poll still sees remote
// increments — WITHOUT the per-iteration L2 invalidate that an ACQUIRE poll
// forces on gfx950 (that was the 720us/barrier pathology: every spin load
// flushed the XCD L2, making all traffic cold-miss at 87 GB/s).
// Exactly two cache-maintenance ops per block per barrier: one release fence
// (L2 writeback) before signaling, one acquire fence (L2 invalidate) after.
__device__ __forceinline__ void gridbar(unsigned* bar) {
  __syncthreads();
  if (threadIdx.x == 0) {
    __threadfence();  // release: make this block's writes visible (L2 wb)
    unsigned old = __hip_atomic_fetch_add(bar, 1u, __ATOMIC_RELAXED,
                                          __HIP_MEMORY_SCOPE_AGENT);
    unsigned need = (old / cNBLK + 1u) * cNBLK;
    while (__hip_atomic_load(bar, __ATOMIC_RELAXED,
                             __HIP_MEMORY_SCOPE_AGENT) < need) {
      __builtin_amdgcn_s_sleep(4);
    }
    __threadfence();  // acquire: invalidate stale cached lines (L2 inv)
  }
  __syncthreads();
}

// ======================= standalone GEMMs (prep / epilogue) =================
enum GemmMode { MQ = 0, MWO, MFF1, MFF2 };

struct GemmArgs {
  const float *A, *A2, *sm, *sr, *g, *b;
  const short *WT, *WT2;   // hi / lo
  const float *bias, *extra;
  float *O;
  short *Os;
};

template<int MODE>
__device__ __forceinline__ float loadA(const GemmArgs& p, int r, int k) {
  if constexpr (MODE == MQ) {
    int t = r >> 9, bb = r & 511;
    float v = (t < cT) ? p.A[((size_t)bb * cT + t) * cD + k]
                       : p.A2[(size_t)bb * cD + k];
    return (v - p.sm[r]) * p.sr[r] * p.g[k] + p.b[k];
  } else if constexpr (MODE == MFF1) {
    return (p.A[(size_t)r * cD + k] - p.sm[r]) * p.sr[r] * p.g[k] + p.b[k];
  } else if constexpr (MODE == MFF2) {
    return p.A[(size_t)r * cFF + k];
  } else {  // MWO
    return p.A[(size_t)r * cD + k];
  }
}

template<int MODE>
__device__ __forceinline__ void epi(const GemmArgs& p, int r, int cn, float acc) {
  if constexpr (MODE == MQ) {
    p.Os[(size_t)r * cD + cn] = f2bf(acc);  // raw q, bf16 (l2n at consumer)
  } else if constexpr (MODE == MWO) {
    p.O[(size_t)r * cD + cn] = p.extra[(size_t)r * cD + cn] + acc + p.bias[cn];
  } else if constexpr (MODE == MFF1) {
    p.O[(size_t)r * cFF + cn] = fmaxf(acc + p.bias[cn], 0.f);
  } else {  // MFF2
    p.O[(size_t)r * cD + cn] = p.extra[(size_t)r * cD + cn] + acc + p.bias[cn];
  }
}

// single-precision bf16 MFMA GEMM (q_all — matches R2 numerics)
template<int MODE, int LDW>
__global__ __launch_bounds__(256) void mgemm(GemmArgs p, int K) {
  __shared__ short As[64][32];
  __shared__ short Bs[64][32];
  const int tid = threadIdx.x;
  const int lane = tid & 63, wid = tid >> 6;
  const int wm = wid & 1, wn = wid >> 1;
  const int l15 = lane & 15, qd = lane >> 4;
  const int row0 = blockIdx.x * 64;
  const int n0 = blockIdx.y * 64;

  f32x4 acc[2][2] = {};
  const int sm = tid >> 2;
  const int sk = (tid & 3) * 8;

  for (int k0 = 0; k0 < K; k0 += 32) {
    {
      short tmp[8];
#pragma unroll
      for (int j = 0; j < 8; ++j)
        tmp[j] = f2bf(loadA<MODE>(p, row0 + sm, k0 + sk + j));
      *((bfrag*)&As[sm][0] + (sk >> 3)) = *(bfrag*)tmp;
    }
    *((bfrag*)&Bs[sm][0] + (sk >> 3)) =
        *(const bfrag*)(p.WT + (size_t)(n0 + sm) * LDW + k0 + sk);
    __syncthreads();
    bfrag a0 = *((bfrag*)&As[wm * 32 + l15][0] + qd);
    bfrag a1 = *((bfrag*)&As[wm * 32 + 16 + l15][0] + qd);
    bfrag b0 = *((bfrag*)&Bs[wn * 32 + l15][0] + qd);
    bfrag b1 = *((bfrag*)&Bs[wn * 32 + 16 + l15][0] + qd);
    acc[0][0] = __builtin_amdgcn_mfma_f32_16x16x32_bf16(a0, b0, acc[0][0], 0, 0, 0);
    acc[0][1] = __builtin_amdgcn_mfma_f32_16x16x32_bf16(a0, b1, acc[0][1], 0, 0, 0);
    acc[1][0] = __builtin_amdgcn_mfma_f32_16x16x32_bf16(a1, b0, acc[1][0], 0, 0, 0);
    acc[1][1] = __builtin_amdgcn_mfma_f32_16x16x32_bf16(a1, b1, acc[1][1], 0, 0, 0);
    __syncthreads();
  }

#pragma unroll
  for (int fm = 0; fm < 2; ++fm)
#pragma unroll
    for (int fn = 0; fn < 2; ++fn)
#pragma unroll
      for (int rg = 0; rg < 4; ++rg)
        epi<MODE>(p, row0 + wm * 32 + fm * 16 + qd * 4 + rg,
                  n0 + wn * 32 + fn * 16 + l15, acc[fm][fn][rg]);
}

// split-precision GEMM (post-scan layers)
template<int MODE, int LDW>
__global__ __launch_bounds__(256) void pgemm(GemmArgs p, int K) {
  __shared__ short Ah[64][32], Al[64][32];
  __shared__ short Bh[64][32], Bl[64][32];
  const int tid = threadIdx.x;
  const int lane = tid & 63, wid = tid >> 6;
  const int wm = wid & 1, wn = wid >> 1;
  const int l15 = lane & 15, qd = lane >> 4;
  const int row0 = blockIdx.x * 64;
  const int n0 = blockIdx.y * 64;

  f32x4 acc[2][2] = {};
  const int sm = tid >> 2;
  const int sk = (tid & 3) * 8;

  for (int k0 = 0; k0 < K; k0 += 32) {
    {
      short th[8], tl[8];
#pragma unroll
      for (int j = 0; j < 8; ++j) {
        float a = loadA<MODE>(p, row0 + sm, k0 + sk + j);
        short h = f2bf(a);
        th[j] = h;
        tl[j] = f2bf(a - bf2f(h));
      }
      *((bfrag*)&Ah[sm][0] + (sk >> 3)) = *(bfrag*)th;
      *((bfrag*)&Al[sm][0] + (sk >> 3)) = *(bfrag*)tl;
    }
    *((bfrag*)&Bh[sm][0] + (sk >> 3)) =
        *(const bfrag*)(p.WT + (size_t)(n0 + sm) * LDW + k0 + sk);
    *((bfrag*)&Bl[sm][0] + (sk >> 3)) =
        *(const bfrag*)(p.WT2 + (size_t)(n0 + sm) * LDW + k0 + sk);
    __syncthreads();
#pragma unroll
    for (int fm = 0; fm < 2; ++fm) {
      bfrag ah = *((bfrag*)&Ah[wm * 32 + fm * 16 + l15][0] + qd);
      bfrag al = *((bfrag*)&Al[wm * 32 + fm * 16 + l15][0] + qd);
#pragma unroll
      for (int fn = 0; fn < 2; ++fn) {
        bfrag bh = *((bfrag*)&Bh[wn * 32 + fn * 16 + l15][0] + qd);
        bfrag bl = *((bfrag*)&Bl[wn * 32 + fn * 16 + l15][0] + qd);
        acc[fm][fn] = __builtin_amdgcn_mfma_f32_16x16x32_bf16(al, bh, acc[fm][fn], 0, 0, 0);
        acc[fm][fn] = __builtin_amdgcn_mfma_f32_16x16x32_bf16(ah, bl, acc[fm][fn], 0, 0, 0);
        acc[fm][fn] = __builtin_amdgcn_mfma_f32_16x16x32_bf16(ah, bh, acc[fm][fn], 0, 0, 0);
      }
    }
    __syncthreads();
  }

#pragma unroll
  for (int fm = 0; fm < 2; ++fm)
#pragma unroll
    for (int fn = 0; fn < 2; ++fn)
#pragma unroll
      for (int rg = 0; rg < 4; ++rg)
        epi<MODE>(p, row0 + wm * 32 + fm * 16 + qd * 4 + rg,
                  n0 + wn * 32 + fn * 16 + l15, acc[fm][fn][rg]);
}

// ======================= weight transpose + bf16 ============================
__global__ __launch_bounds__(256) void tconv(const float* __restrict__ W,
                                             short* __restrict__ WT, int K, int N) {
  __shared__ float tile[32][33];
  int k0 = blockIdx.x * 32, n0 = blockIdx.y * 32;
  int tx = threadIdx.x & 31, ty = threadIdx.x >> 5;
#pragma unroll
  for (int j = 0; j < 32; j += 8) {
    int k = k0 + ty + j, n = n0 + tx;
    tile[ty + j][tx] = (k < K && n < N) ? W[(size_t)k * N + n] : 0.f;
  }
  __syncthreads();
#pragma unroll
  for (int j = 0; j < 32; j += 8) {
    int n = n0 + ty + j, k = k0 + tx;
    if (n < N && k < K) WT[(size_t)n * K + k] = f2bf(tile[tx][ty + j]);
  }
}

__global__ __launch_bounds__(256) void tconv2(const float* __restrict__ W,
                                              short* __restrict__ WTh,
                                              short* __restrict__ WTl, int K, int N) {
  __shared__ float tile[32][33];
  int k0 = blockIdx.x * 32, n0 = blockIdx.y * 32;
  int tx = threadIdx.x & 31, ty = threadIdx.x >> 5;
#pragma unroll
  for (int j = 0; j < 32; j += 8) {
    int k = k0 + ty + j, n = n0 + tx;
    tile[ty + j][tx] = (k < K && n < N) ? W[(size_t)k * N + n] : 0.f;
  }
  __syncthreads();
#pragma unroll
  for (int j = 0; j < 32; j += 8) {
    int n = n0 + ty + j, k = k0 + tx;
    if (n < N && k < K) {
      float v = tile[tx][ty + j];
      short h = f2bf(v);
      WTh[(size_t)n * K + k] = h;
      WTl[(size_t)n * K + k] = f2bf(v - bf2f(h));
    }
  }
}

// ======================= LN stats + us_norm =================================
__global__ __launch_bounds__(256) void ln_stats_k(
    const float* __restrict__ item_seq, const float* __restrict__ last_item,
    const float* __restrict__ user, const float* __restrict__ n1g,
    const float* __restrict__ n1b, float* __restrict__ lnm,
    float* __restrict__ lnr, float* __restrict__ us_norm) {
  const int lane = threadIdx.x & 63;
  const int w = blockIdx.x * 4 + (threadIdx.x >> 6);
  const float* src;
  int cls, bi = 0;
  if (w < cT * cB) {
    int t = w >> 9, bb = w & 511;
    src = item_seq + ((size_t)bb * cT + t) * cD;
    cls = 0;
  } else if (w < cT * cB + cB) {
    bi = w - cT * cB;
    src = last_item + (size_t)bi * cD;
    cls = 1;
  } else {
    bi = w - cT * cB - cB;
    src = user + (size_t)bi * cD;
    cls = 2;
  }
  float x[8], s = 0.f, ss = 0.f;
#pragma unroll
  for (int i = 0; i < 8; ++i) {
    float v = src[lane + i * 64];
    x[i] = v; s += v; ss += v * v;
  }
#pragma unroll
  for (int o = 32; o >= 1; o >>= 1) { s += __shfl_xor(s, o); ss += __shfl_xor(ss, o); }
  float m = s * (1.f / cD);
  float rstd = rsqrtf(ss * (1.f / cD) - m * m + 1e-5f);
  if (cls == 0) {
    if (lane == 0) { lnm[w] = m; lnr[w] = rstd; }
  } else if (cls == 1) {
    if (lane == 0) { lnm[cT * cB + bi] = m; lnr[cT * cB + bi] = rstd; }
  } else {
#pragma unroll
    for (int i = 0; i < 8; ++i) {
      int d = lane + i * 64;
      us_norm[(size_t)bi * cD + d] = (x[i] - m) * rstd * n1g[d] + n1b[d];
    }
  }
}

// ======================= per-row stats ======================================
__global__ __launch_bounds__(256) void row_stats_k(const float* __restrict__ X,
                                                   float* __restrict__ M,
                                                   float* __restrict__ R) {
  const int lane = threadIdx.x & 63;
  const int w = blockIdx.x * 4 + (threadIdx.x >> 6);
  float s = 0.f, ss = 0.f;
#pragma unroll
  for (int i = 0; i < 8; ++i) {
    float v = X[(size_t)w * cD + lane + i * 64];
    s += v; ss += v * v;
  }
#pragma unroll
  for (int o = 32; o >= 1; o >>= 1) { s += __shfl_xor(s, o); ss += __shfl_xor(ss, o); }
  if (lane == 0) {
    float m = s * (1.f / cD);
    M[w] = m;
    R[w] = rsqrtf(ss * (1.f / cD) - m * m + 1e-5f);
  }
}

// ======================= cooperative-style scan kernel ======================
struct ScanParams {
  const float *item_seq, *init_state;
  const float *lnm, *lnr, *n1g, *n1b, *us_norm;
  const float *mcb1, *mcg, *mcbt, *mcb2, *ba, *be;
  const short *wt_m1, *wt_m1l, *wt_m2, *wt_m2l, *wt_kvae, *wt_kvael, *q_all;
  float *mem_ctx, *r_buf, *mo_buf;
  float *k_raw, *v_buf, *alpha_b, *eta_b, *state;
  unsigned *bar;
};

template<int PH>
__device__ __forceinline__ float ldA(const ScanParams& p, int t, int r, int k,
                                     const float* rmL, const float* rrL) {
  if constexpr (PH == 1) {  // [us_norm | mem_ctx]
    return (k < cD) ? p.us_norm[(size_t)r * cD + k]
                    : p.mem_ctx[(size_t)r * cD + (k - cD)];
  } else if constexpr (PH == 3) {  // relu(LN(r_buf)) with LDS stats
    float v = (p.r_buf[(size_t)r * cD + k] - rmL[r & 63]) * rrL[r & 63] *
                  p.mcg[k] + p.mcbt[k];
    return fmaxf(v, 0.f);
  } else {  // PH == 4: mod = i_norm*(1+tanh(gamma)) + beta
    float inm = (p.item_seq[((size_t)r * cT + t) * cD + k] - p.lnm[t * cB + r]) *
                    p.lnr[t * cB + r] * p.n1g[k] + p.n1b[k];
    float gam = p.mo_buf[(size_t)r * 1040 + k];
    float bet = p.mo_buf[(size_t)r * 1040 + 512 + k];
    return inm * (1.f + tanhf(gam)) + bet;
  }
}

// split-precision scan GEMM phase: A,W = bf16 hi+lo, 3 MFMAs per frag
template<int PH, int K>
__device__ void gemm_phase(const ScanParams& p, int t, int row0, int n0,
                           short (*Ah)[32], short (*Al)[32],
                           short (*Bh)[32], short (*Bl)[32],
                           const float* rmL, const float* rrL) {
  const int tid = threadIdx.x;
  const int lane = tid & 63, wid = tid >> 6;
  const int wm = wid & 1, wn = wid >> 1;
  const int l15 = lane & 15, qd = lane >> 4;

  f32x4 acc[2][2] = {};
  const int sm = tid >> 2;
  const int sk = (tid & 3) * 8;

  for (int k0 = 0; k0 < K; k0 += 32) {
    {
      short th[8], tl[8];
#pragma unroll
      for (int j = 0; j < 8; ++j) {
        float a = ldA<PH>(p, t, row0 + sm, k0 + sk + j, rmL, rrL);
        short h = f2bf(a);
        th[j] = h;
        tl[j] = f2bf(a - bf2f(h));
      }
      *((bfrag*)&Ah[sm][0] + (sk >> 3)) = *(bfrag*)th;
      *((bfrag*)&Al[sm][0] + (sk >> 3)) = *(bfrag*)tl;
    }
    {
      bfrag wh = {}, wl = {};
      if (PH == 1) {
        wh = *(const bfrag*)(p.wt_m1 + (size_t)(n0 + sm) * 1024 + k0 + sk);
        wl = *(const bfrag*)(p.wt_m1l + (size_t)(n0 + sm) * 1024 + k0 + sk);
      } else if (n0 + sm < 1040) {
        const short* wth = (PH == 3) ? p.wt_m2 : p.wt_kvae;
        const short* wtl = (PH == 3) ? p.wt_m2l : p.wt_kvael;
        wh = *(const bfrag*)(wth + (size_t)(n0 + sm) * 512 + k0 + sk);
        wl = *(const bfrag*)(wtl + (size_t)(n0 + sm) * 512 + k0 + sk);
      }
      *((bfrag*)&Bh[sm][0] + (sk >> 3)) = wh;
      *((bfrag*)&Bl[sm][0] + (sk >> 3)) = wl;
    }
    __syncthreads();
#pragma unroll
    for (int fm = 0; fm < 2; ++fm) {
      bfrag ah = *((bfrag*)&Ah[wm * 32 + fm * 16 + l15][0] + qd);
      bfrag al = *((bfrag*)&Al[wm * 32 + fm * 16 + l15][0] + qd);
#pragma unroll
      for (int fn = 0; fn < 2; ++fn) {
        bfrag bh = *((bfrag*)&Bh[wn * 32 + fn * 16 + l15][0] + qd);
        bfrag bl = *((bfrag*)&Bl[wn * 32 + fn * 16 + l15][0] + qd);
        acc[fm][fn] = __builtin_amdgcn_mfma_f32_16x16x32_bf16(al, bh, acc[fm][fn], 0, 0, 0);
        acc[fm][fn] = __builtin_amdgcn_mfma_f32_16x16x32_bf16(ah, bl, acc[fm][fn], 0, 0, 0);
        acc[fm][fn] = __builtin_amdgcn_mfma_f32_16x16x32_bf16(ah, bh, acc[fm][fn], 0, 0, 0);
      }
    }
    __syncthreads();
  }

#pragma unroll
  for (int fm = 0; fm < 2; ++fm)
#pragma unroll
    for (int fn = 0; fn < 2; ++fn)
#pragma unroll
      for (int rg = 0; rg < 4; ++rg) {
        int r = row0 + wm * 32 + fm * 16 + qd * 4 + rg;
        int cn = n0 + wn * 32 + fn * 16 + l15;
        float a = acc[fm][fn][rg];
        if constexpr (PH == 1) {
          p.r_buf[(size_t)r * cD + cn] = a + p.mcb1[cn];
        } else if constexpr (PH == 3) {
          if (cn < 1040) p.mo_buf[(size_t)r * 1040 + cn] = a + p.mcb2[cn];
        } else {  // PH == 4
          if (cn < 512) {
            p.k_raw[(size_t)r * cD + cn] = a;
          } else if (cn < 1024) {
            p.v_buf[(size_t)r * cD + (cn - 512)] = a;
          } else if (cn < 1032) {
            int h = cn - 1024;
            p.alpha_b[r * cH + h] = sigm(a + p.ba[h] + p.mo_buf[(size_t)r * 1040 + 1024 + h]);
          } else if (cn < 1040) {
            int h = cn - 1032;
            p.eta_b[r * cH + h] =
                cSCALE * sigm(a + p.be[h] + p.mo_buf[(size_t)r * 1040 + 1032 + h]);
          }
        }
      }
}

template<bool UPD>
__device__ void state_phase(const ScanParams& p, const float* __restrict__ Sin,
                            int qslot, float (*skq)[4][64]) {
  const int lane = threadIdx.x & 63;
  const int wi = threadIdx.x >> 6;
  const int w = blockIdx.x * 4 + wi;
  const int b = w >> 3, h = w & 7;

  float q = bf2f(p.q_all[(size_t)qslot * cB * cD + (size_t)b * cD + h * cDH + lane]);
  float qs = q * q;
#pragma unroll
  for (int o = 32; o >= 1; o >>= 1) qs += __shfl_xor(qs, o);
  skq[0][wi][lane] = q / fmaxf(sqrtf(qs), 1e-12f);

  if constexpr (UPD) {
    float kv = p.k_raw[(size_t)b * cD + h * cDH + lane];
    float ks = kv * kv;
#pragma unroll
    for (int o = 32; o >= 1; o >>= 1) ks += __shfl_xor(ks, o);
    skq[1][wi][lane] = kv / fmaxf(sqrtf(ks), 1e-12f);
  }

  float S[64];
  const float* sp = Sin + ((size_t)w * cDH + lane) * cDH;
#pragma unroll
  for (int j = 0; j < 64; j += 4) {
    float4 t4 = *(const float4*)(sp + j);
    S[j] = t4.x; S[j + 1] = t4.y; S[j + 2] = t4.z; S[j + 3] = t4.w;
  }

  float mem = 0.f;
  if constexpr (UPD) {
    float vv = p.v_buf[(size_t)b * cD + h * cDH + lane];
    float a = p.alpha_b[b * cH + h];
    float e = p.eta_b[b * cH + h];
    float pred = 0.f;
#pragma unroll
    for (int j = 0; j < 64; ++j) pred += S[j] * skq[1][wi][j];
    float f = e * (vv - pred);
    float oma = 1.f - a;
#pragma unroll
    for (int j = 0; j < 64; ++j) {
      S[j] = oma * S[j] + f * skq[1][wi][j];
      mem += S[j] * skq[0][wi][j];
    }
    float* op = p.state + ((size_t)w * cDH + lane) * cDH;
#pragma unroll
    for (int j = 0; j < 64; j += 4) {
      float4 t4 = make_float4(S[j], S[j + 1], S[j + 2], S[j + 3]);
      *(float4*)(op + j) = t4;
    }
  } else {
#pragma unroll
    for (int j = 0; j < 64; ++j) mem += S[j] * skq[0][wi][j];
  }
  p.mem_ctx[(size_t)b * cD + h * cDH + lane] = mem;
}

__global__ __launch_bounds__(256, 4) void scan_k(ScanParams p) {
  __shared__ short Ah[64][32], Al[64][32];
  __shared__ short Bh[64][32], Bl[64][32];
  __shared__ float skq[2][4][64];
  __shared__ float rmL[64], rrL[64];
  const int bid = blockIdx.x;

  // mem_ctx_0 = read(init_state, q_0)
  state_phase<false>(p, p.init_state, 0, skq);
  gridbar(p.bar);

  for (int t = 0; t < cT; ++t) {
    if (bid < 64)  // P1: meta1, full K=1024
      gemm_phase<1, 1024>(p, t, (bid >> 3) * 64, (bid & 7) * 64,
                          Ah, Al, Bh, Bl, nullptr, nullptr);
    gridbar(p.bar);
    if (bid < 136) {  // P3: meta2 + in-block LN stats of its 64 rows
      int row0 = (bid & 7) * 64;
      int lane = threadIdx.x & 63, wid = threadIdx.x >> 6;
      for (int rr2 = 0; rr2 < 16; ++rr2) {
        int row = row0 + wid * 16 + rr2;
        float s = 0.f, ss = 0.f;
#pragma unroll
        for (int i = 0; i < 8; ++i) {
          float v = p.r_buf[(size_t)row * cD + lane + i * 64];
          s += v; ss += v * v;
        }
#pragma unroll
        for (int o = 32; o >= 1; o >>= 1) { s += __shfl_xor(s, o); ss += __shfl_xor(ss, o); }
        if (lane == 0) {
          float m = s * (1.f / cD);
          rmL[wid * 16 + rr2] = m;
          rrL[wid * 16 + rr2] = rsqrtf(ss * (1.f / cD) - m * m + 1e-5f);
        }
      }
      __syncthreads();
      gemm_phase<3, 512>(p, t, row0, (bid >> 3) * 64, Ah, Al, Bh, Bl, rmL, rrL);
    }
    gridbar(p.bar);
    if (bid < 136)  // P4: kvae (mod fused into A-load)
      gemm_phase<4, 512>(p, t, (bid & 7) * 64, (bid >> 3) * 64,
                         Ah, Al, Bh, Bl, nullptr, nullptr);
    gridbar(p.bar);
    // P5: state update + read with q_{t+1}
    state_phase<true>(p, (t == 0) ? p.init_state : p.state, t + 1, skq);
    gridbar(p.bar);
  }
}

// ======================= host launch ========================================
extern "C" void kernel_launch(void* const* d_in, const int* in_sizes, int n_in,
                              void* d_out, int out_size, void* d_ws, size_t ws_size,
                              hipStream_t stream) {
  (void)in_sizes; (void)n_in; (void)out_size;
  const float* item_seq   = (const float*)d_in[0];
  const float* user_stat  = (const float*)d_in[1];
  const float* last_item  = (const float*)d_in[2];
  const float* init_state = (const float*)d_in[3];
  const float* Wq  = (const float*)d_in[4];
  const float* Wk  = (const float*)d_in[5];
  const float* Wv  = (const float*)d_in[6];
  const float* Wa  = (const float*)d_in[7];
  const float* ba  = (const float*)d_in[8];
  const float* We  = (const float*)d_in[9];
  const float* be  = (const float*)d_in[10];
  const float* mcW1 = (const float*)d_in[11];
  const float* mcb1 = (const float*)d_in[12];
  const float* mcg  = (const float*)d_in[13];
  const float* mcbt = (const float*)d_in[14];
  const float* mcW2 = (const float*)d_in[15];
  const float* mcb2 = (const float*)d_in[16];
  const float* Wo  = (const float*)d_in[17];
  const float* bo  = (const float*)d_in[18];
  const float* W1  = (const float*)d_in[19];
  const float* b1  = (const float*)d_in[20];
  const float* W2  = (const float*)d_in[21];
  const float* b2  = (const float*)d_in[22];
  const float* n1g = (const float*)d_in[23];
  const float* n1b = (const float*)d_in[24];
  const float* n2g = (const float*)d_in[25];
  const float* n2b = (const float*)d_in[26];

  float* ws = (float*)d_ws;
  size_t off = 0;
  auto alloc = [&](size_t n) { float* p = ws + off; off += n; return p; };
  auto salloc = [&](size_t n) { return (short*)alloc((n + 1) / 2); };

  unsigned* bar  = (unsigned*)alloc(16);  // 64B, zeroed below
  short* q_all   = salloc((size_t)(cT + 1) * cB * cD);
  float* state   = alloc((size_t)cB * cH * cDH * cDH);
  float* lnm     = alloc((size_t)(cT + 1) * cB);
  float* lnr     = alloc((size_t)(cT + 1) * cB);
  float* us_norm = alloc((size_t)cB * cD);
  float* mem_ctx = alloc((size_t)cB * cD);
  float* r_buf   = alloc((size_t)cB * cD);
  float* mo_buf  = alloc((size_t)cB * 1040);
  float* k_raw   = alloc((size_t)cB * cD);
  float* v_buf   = alloc((size_t)cB * cD);
  float* alpha_b = alloc((size_t)cB * cH);
  float* eta_b   = alloc((size_t)cB * cH);
  float* x_buf   = alloc((size_t)cB * cD);
  float* xm      = alloc(cB);
  float* xr      = alloc(cB);
  float* u_buf   = alloc((size_t)cB * cFF);
  short* wt_q    = salloc((size_t)512 * 512);
  short* wt_m1   = salloc((size_t)512 * 1024);
  short* wt_m1l  = salloc((size_t)512 * 1024);
  short* wt_m2   = salloc((size_t)1040 * 512);
  short* wt_m2l  = salloc((size_t)1040 * 512);
  short* wt_kvae = salloc((size_t)1040 * 512);
  short* wt_kvael= salloc((size_t)1040 * 512);
  short* wt_o    = salloc((size_t)512 * 512);
  short* wt_o_l  = salloc((size_t)512 * 512);
  short* wt_1    = salloc((size_t)2048 * 512);
  short* wt_1_l  = salloc((size_t)2048 * 512);
  short* wt_2    = salloc((size_t)512 * 2048);
  short* wt_2_l  = salloc((size_t)512 * 2048);
  if (ws_size < off * sizeof(float)) return;

  hipMemsetAsync(bar, 0, 64, stream);  // zero the grid barrier counter

  // --- prep ---
  tconv<<<dim3(16, 16), 256, 0, stream>>>(Wq, wt_q, 512, 512);
  tconv2<<<dim3(32, 16), 256, 0, stream>>>(mcW1, wt_m1, wt_m1l, 1024, 512);
  tconv2<<<dim3(16, 33), 256, 0, stream>>>(mcW2, wt_m2, wt_m2l, 512, 1040);
  tconv2<<<dim3(16, 16), 256, 0, stream>>>(Wk, wt_kvae, wt_kvael, 512, 512);
  tconv2<<<dim3(16, 16), 256, 0, stream>>>(Wv, wt_kvae + (size_t)512 * 512,
                                           wt_kvael + (size_t)512 * 512, 512, 512);
  tconv2<<<dim3(16, 1), 256, 0, stream>>>(Wa, wt_kvae + (size_t)1024 * 512,
                                          wt_kvael + (size_t)1024 * 512, 512, 8);
  tconv2<<<dim3(16, 1), 256, 0, stream>>>(We, wt_kvae + (size_t)1032 * 512,
                                          wt_kvael + (size_t)1032 * 512, 512, 8);
  tconv2<<<dim3(16, 16), 256, 0, stream>>>(Wo, wt_o, wt_o_l, 512, 512);
  tconv2<<<dim3(16, 64), 256, 0, stream>>>(W1, wt_1, wt_1_l, 512, 2048);
  tconv2<<<dim3(64, 16), 256, 0, stream>>>(W2, wt_2, wt_2_l, 2048, 512);

  ln_stats_k<<<(cT * cB + 2 * cB) / 4, 256, 0, stream>>>(
      item_seq, last_item, user_stat, n1g, n1b, lnm, lnr, us_norm);

  {  // q_all for all 65 slots (bf16 out)
    GemmArgs p{}; p.A = item_seq; p.A2 = last_item; p.sm = lnm; p.sr = lnr;
    p.g = n1g; p.b = n1b; p.WT = wt_q; p.Os = q_all;
    mgemm<MQ, 512><<<dim3(520, 8), 256, 0, stream>>>(p, 512);
  }

  {  // --- the whole 64-step scan, one kernel with custom grid barrier ---
    ScanParams sp{};
    sp.item_seq = item_seq; sp.init_state = init_state;
    sp.lnm = lnm; sp.lnr = lnr; sp.n1g = n1g; sp.n1b = n1b; sp.us_norm = us_norm;
    sp.mcb1 = mcb1; sp.mcg = mcg; sp.mcbt = mcbt; sp.mcb2 = mcb2;
    sp.ba = ba; sp.be = be;
    sp.wt_m1 = wt_m1; sp.wt_m1l = wt_m1l; sp.wt_m2 = wt_m2; sp.wt_m2l = wt_m2l;
    sp.wt_kvae = wt_kvae; sp.wt_kvael = wt_kvael; sp.q_all = q_all;
    sp.mem_ctx = mem_ctx; sp.r_buf = r_buf; sp.mo_buf = mo_buf;
    sp.k_raw = k_raw; sp.v_buf = v_buf;
    sp.alpha_b = alpha_b; sp.eta_b = eta_b; sp.state = state;
    sp.bar = bar;
    scan_k<<<dim3(cNBLK), dim3(256), 0, stream>>>(sp);
  }

  {  // x = user + mem_ctx @ Wo + bo  (split precision)
    GemmArgs p{}; p.A = mem_ctx; p.WT = wt_o; p.WT2 = wt_o_l;
    p.bias = bo; p.extra = user_stat; p.O = x_buf;
    pgemm<MWO, 512><<<dim3(8, 8), 256, 0, stream>>>(p, 512);
  }
  row_stats_k<<<cB / 4, 256, 0, stream>>>(x_buf, xm, xr);
  {  // u = relu(LN(x) @ W1 + b1)  (split precision)
    GemmArgs p{}; p.A = x_buf; p.sm = xm; p.sr = xr; p.g = n2g; p.b = n2b;
    p.WT = wt_1; p.WT2 = wt_1_l; p.bias = b1; p.O = u_buf;
    pgemm<MFF1, 512><<<dim3(8, 32), 256, 0, stream>>>(p, 512);
  }
  {  // out = x + u @ W2 + b2  (split precision)
    GemmArgs p{}; p.A = u_buf; p.WT = wt_2; p.WT2 = wt_2_l;
    p.bias = b2; p.extra = x_buf; p.O = (float*)d_out;
    pgemm<MFF2, 2048><<<dim3(8, 8), 256, 0, stream>>>(p, 2048);
  }
}

// Round 7
// 7085.836 us; speedup vs baseline: 26.1024x; 5.0530x over previous
//
#include <hip/hip_runtime.h>
#include <cmath>

constexpr int cB = 512, cT = 64, cD = 512, cH = 8, cDH = 64, cFF = 2048;
constexpr float cSCALE = 0.125f;  // DH^-0.5

typedef short bfrag __attribute__((ext_vector_type(8)));   // 8 bf16 = 4 VGPRs
typedef float f32x4 __attribute__((ext_vector_type(4)));

__device__ __forceinline__ short f2bf(float x) {
  union { float f; unsigned u; } v{x};
  unsigned r = v.u + 0x7fff + ((v.u >> 16) & 1);
  return (short)(r >> 16);
}
__device__ __forceinline__ float bf2f(short s) {
  union { unsigned u; float f; } v;
  v.u = ((unsigned)(unsigned short)s) << 16;
  return v.f;
}
__device__ __forceinline__ float sigm(float z) { return 1.f / (1.f + __expf(-z)); }

// ======================= standalone GEMMs (prep / epilogue) =================
enum GemmMode { MQ = 0, MWO, MFF1, MFF2 };

struct GemmArgs {
  const float *A, *A2, *sm, *sr, *g, *b;
  const short *WT, *WT2;   // hi / lo
  const float *bias, *extra;
  float *O;
  short *Os;
};

template<int MODE>
__device__ __forceinline__ float loadA(const GemmArgs& p, int r, int k) {
  if constexpr (MODE == MQ) {
    int t = r >> 9, bb = r & 511;
    float v = (t < cT) ? p.A[((size_t)bb * cT + t) * cD + k]
                       : p.A2[(size_t)bb * cD + k];
    return (v - p.sm[r]) * p.sr[r] * p.g[k] + p.b[k];
  } else if constexpr (MODE == MFF1) {
    return (p.A[(size_t)r * cD + k] - p.sm[r]) * p.sr[r] * p.g[k] + p.b[k];
  } else if constexpr (MODE == MFF2) {
    return p.A[(size_t)r * cFF + k];
  } else {  // MWO
    return p.A[(size_t)r * cD + k];
  }
}

template<int MODE>
__device__ __forceinline__ void epi(const GemmArgs& p, int r, int cn, float acc) {
  if constexpr (MODE == MQ) {
    p.Os[(size_t)r * cD + cn] = f2bf(acc);  // raw q, bf16 (l2n at consumer)
  } else if constexpr (MODE == MWO) {
    p.O[(size_t)r * cD + cn] = p.extra[(size_t)r * cD + cn] + acc + p.bias[cn];
  } else if constexpr (MODE == MFF1) {
    p.O[(size_t)r * cFF + cn] = fmaxf(acc + p.bias[cn], 0.f);
  } else {  // MFF2
    p.O[(size_t)r * cD + cn] = p.extra[(size_t)r * cD + cn] + acc + p.bias[cn];
  }
}

// single-precision bf16 MFMA GEMM (q_all — matches R2/R6 numerics)
template<int MODE, int LDW>
__global__ __launch_bounds__(256) void mgemm(GemmArgs p, int K) {
  __shared__ short As[64][32];
  __shared__ short Bs[64][32];
  const int tid = threadIdx.x;
  const int lane = tid & 63, wid = tid >> 6;
  const int wm = wid & 1, wn = wid >> 1;
  const int l15 = lane & 15, qd = lane >> 4;
  const int row0 = blockIdx.x * 64;
  const int n0 = blockIdx.y * 64;

  f32x4 acc[2][2] = {};
  const int sm = tid >> 2;
  const int sk = (tid & 3) * 8;

  for (int k0 = 0; k0 < K; k0 += 32) {
    {
      short tmp[8];
#pragma unroll
      for (int j = 0; j < 8; ++j)
        tmp[j] = f2bf(loadA<MODE>(p, row0 + sm, k0 + sk + j));
      *((bfrag*)&As[sm][0] + (sk >> 3)) = *(bfrag*)tmp;
    }
    *((bfrag*)&Bs[sm][0] + (sk >> 3)) =
        *(const bfrag*)(p.WT + (size_t)(n0 + sm) * LDW + k0 + sk);
    __syncthreads();
    bfrag a0 = *((bfrag*)&As[wm * 32 + l15][0] + qd);
    bfrag a1 = *((bfrag*)&As[wm * 32 + 16 + l15][0] + qd);
    bfrag b0 = *((bfrag*)&Bs[wn * 32 + l15][0] + qd);
    bfrag b1 = *((bfrag*)&Bs[wn * 32 + 16 + l15][0] + qd);
    acc[0][0] = __builtin_amdgcn_mfma_f32_16x16x32_bf16(a0, b0, acc[0][0], 0, 0, 0);
    acc[0][1] = __builtin_amdgcn_mfma_f32_16x16x32_bf16(a0, b1, acc[0][1], 0, 0, 0);
    acc[1][0] = __builtin_amdgcn_mfma_f32_16x16x32_bf16(a1, b0, acc[1][0], 0, 0, 0);
    acc[1][1] = __builtin_amdgcn_mfma_f32_16x16x32_bf16(a1, b1, acc[1][1], 0, 0, 0);
    __syncthreads();
  }

#pragma unroll
  for (int fm = 0; fm < 2; ++fm)
#pragma unroll
    for (int fn = 0; fn < 2; ++fn)
#pragma unroll
      for (int rg = 0; rg < 4; ++rg)
        epi<MODE>(p, row0 + wm * 32 + fm * 16 + qd * 4 + rg,
                  n0 + wn * 32 + fn * 16 + l15, acc[fm][fn][rg]);
}

// split-precision GEMM (post-scan layers; unchanged from R6 — passed)
template<int MODE, int LDW>
__global__ __launch_bounds__(256) void pgemm(GemmArgs p, int K) {
  __shared__ short Ah[64][32], Al[64][32];
  __shared__ short Bh[64][32], Bl[64][32];
  const int tid = threadIdx.x;
  const int lane = tid & 63, wid = tid >> 6;
  const int wm = wid & 1, wn = wid >> 1;
  const int l15 = lane & 15, qd = lane >> 4;
  const int row0 = blockIdx.x * 64;
  const int n0 = blockIdx.y * 64;

  f32x4 acc[2][2] = {};
  const int sm = tid >> 2;
  const int sk = (tid & 3) * 8;

  for (int k0 = 0; k0 < K; k0 += 32) {
    {
      short th[8], tl[8];
#pragma unroll
      for (int j = 0; j < 8; ++j) {
        float a = loadA<MODE>(p, row0 + sm, k0 + sk + j);
        short h = f2bf(a);
        th[j] = h;
        tl[j] = f2bf(a - bf2f(h));
      }
      *((bfrag*)&Ah[sm][0] + (sk >> 3)) = *(bfrag*)th;
      *((bfrag*)&Al[sm][0] + (sk >> 3)) = *(bfrag*)tl;
    }
    *((bfrag*)&Bh[sm][0] + (sk >> 3)) =
        *(const bfrag*)(p.WT + (size_t)(n0 + sm) * LDW + k0 + sk);
    *((bfrag*)&Bl[sm][0] + (sk >> 3)) =
        *(const bfrag*)(p.WT2 + (size_t)(n0 + sm) * LDW + k0 + sk);
    __syncthreads();
#pragma unroll
    for (int fm = 0; fm < 2; ++fm) {
      bfrag ah = *((bfrag*)&Ah[wm * 32 + fm * 16 + l15][0] + qd);
      bfrag al = *((bfrag*)&Al[wm * 32 + fm * 16 + l15][0] + qd);
#pragma unroll
      for (int fn = 0; fn < 2; ++fn) {
        bfrag bh = *((bfrag*)&Bh[wn * 32 + fn * 16 + l15][0] + qd);
        bfrag bl = *((bfrag*)&Bl[wn * 32 + fn * 16 + l15][0] + qd);
        acc[fm][fn] = __builtin_amdgcn_mfma_f32_16x16x32_bf16(al, bh, acc[fm][fn], 0, 0, 0);
        acc[fm][fn] = __builtin_amdgcn_mfma_f32_16x16x32_bf16(ah, bl, acc[fm][fn], 0, 0, 0);
        acc[fm][fn] = __builtin_amdgcn_mfma_f32_16x16x32_bf16(ah, bh, acc[fm][fn], 0, 0, 0);
      }
    }
    __syncthreads();
  }

#pragma unroll
  for (int fm = 0; fm < 2; ++fm)
#pragma unroll
    for (int fn = 0; fn < 2; ++fn)
#pragma unroll
      for (int rg = 0; rg < 4; ++rg)
        epi<MODE>(p, row0 + wm * 32 + fm * 16 + qd * 4 + rg,
                  n0 + wn * 32 + fn * 16 + l15, acc[fm][fn][rg]);
}

// ======================= weight transpose + bf16 ============================
__global__ __launch_bounds__(256) void tconv(const float* __restrict__ W,
                                             short* __restrict__ WT, int K, int N) {
  __shared__ float tile[32][33];
  int k0 = blockIdx.x * 32, n0 = blockIdx.y * 32;
  int tx = threadIdx.x & 31, ty = threadIdx.x >> 5;
#pragma unroll
  for (int j = 0; j < 32; j += 8) {
    int k = k0 + ty + j, n = n0 + tx;
    tile[ty + j][tx] = (k < K && n < N) ? W[(size_t)k * N + n] : 0.f;
  }
  __syncthreads();
#pragma unroll
  for (int j = 0; j < 32; j += 8) {
    int n = n0 + ty + j, k = k0 + tx;
    if (n < N && k < K) WT[(size_t)n * K + k] = f2bf(tile[tx][ty + j]);
  }
}

__global__ __launch_bounds__(256) void tconv2(const float* __restrict__ W,
                                              short* __restrict__ WTh,
                                              short* __restrict__ WTl, int K, int N) {
  __shared__ float tile[32][33];
  int k0 = blockIdx.x * 32, n0 = blockIdx.y * 32;
  int tx = threadIdx.x & 31, ty = threadIdx.x >> 5;
#pragma unroll
  for (int j = 0; j < 32; j += 8) {
    int k = k0 + ty + j, n = n0 + tx;
    tile[ty + j][tx] = (k < K && n < N) ? W[(size_t)k * N + n] : 0.f;
  }
  __syncthreads();
#pragma unroll
  for (int j = 0; j < 32; j += 8) {
    int n = n0 + ty + j, k = k0 + tx;
    if (n < N && k < K) {
      float v = tile[tx][ty + j];
      short h = f2bf(v);
      WTh[(size_t)n * K + k] = h;
      WTl[(size_t)n * K + k] = f2bf(v - bf2f(h));
    }
  }
}

// ======================= LN stats + us_norm =================================
__global__ __launch_bounds__(256) void ln_stats_k(
    const float* __restrict__ item_seq, const float* __restrict__ last_item,
    const float* __restrict__ user, const float* __restrict__ n1g,
    const float* __restrict__ n1b, float* __restrict__ lnm,
    float* __restrict__ lnr, float* __restrict__ us_norm) {
  const int lane = threadIdx.x & 63;
  const int w = blockIdx.x * 4 + (threadIdx.x >> 6);
  const float* src;
  int cls, bi = 0;
  if (w < cT * cB) {
    int t = w >> 9, bb = w & 511;
    src = item_seq + ((size_t)bb * cT + t) * cD;
    cls = 0;
  } else if (w < cT * cB + cB) {
    bi = w - cT * cB;
    src = last_item + (size_t)bi * cD;
    cls = 1;
  } else {
    bi = w - cT * cB - cB;
    src = user + (size_t)bi * cD;
    cls = 2;
  }
  float x[8], s = 0.f, ss = 0.f;
#pragma unroll
  for (int i = 0; i < 8; ++i) {
    float v = src[lane + i * 64];
    x[i] = v; s += v; ss += v * v;
  }
#pragma unroll
  for (int o = 32; o >= 1; o >>= 1) { s += __shfl_xor(s, o); ss += __shfl_xor(ss, o); }
  float m = s * (1.f / cD);
  float rstd = rsqrtf(ss * (1.f / cD) - m * m + 1e-5f);
  if (cls == 0) {
    if (lane == 0) { lnm[w] = m; lnr[w] = rstd; }
  } else if (cls == 1) {
    if (lane == 0) { lnm[cT * cB + bi] = m; lnr[cT * cB + bi] = rstd; }
  } else {
#pragma unroll
    for (int i = 0; i < 8; ++i) {
      int d = lane + i * 64;
      us_norm[(size_t)bi * cD + d] = (x[i] - m) * rstd * n1g[d] + n1b[d];
    }
  }
}

// ======================= per-row stats ======================================
__global__ __launch_bounds__(256) void row_stats_k(const float* __restrict__ X,
                                                   float* __restrict__ M,
                                                   float* __restrict__ R) {
  const int lane = threadIdx.x & 63;
  const int w = blockIdx.x * 4 + (threadIdx.x >> 6);
  float s = 0.f, ss = 0.f;
#pragma unroll
  for (int i = 0; i < 8; ++i) {
    float v = X[(size_t)w * cD + lane + i * 64];
    s += v; ss += v * v;
  }
#pragma unroll
  for (int o = 32; o >= 1; o >>= 1) { s += __shfl_xor(s, o); ss += __shfl_xor(ss, o); }
  if (lane == 0) {
    float m = s * (1.f / cD);
    M[w] = m;
    R[w] = rsqrtf(ss * (1.f / cD) - m * m + 1e-5f);
  }
}

// ======================= barrier-free per-batch scan ========================
// One block per 2 batch elements. Wave w = (bb = w>>3, h = w&7) holds state
// S[b0+bb][h] in VGPRs (lane i = row i, 64 fp32). All activations in LDS.
// GEMVs run as M=2 MFMA GEMMs (A rows 0,1 = the 2 batch rows). No grid sync,
// no fences — blocks fully independent; weights (bf16 WT[n][k], ~3.1 MB)
// stay resident in each XCD's 4 MB L2.
struct Scan2Params {
  const float *item_seq, *init_state, *us_norm, *lnm, *lnr, *n1g, *n1b;
  const float *mcb1, *mcg, *mcbt, *mcb2, *ba, *be;
  const short *wt_m1, *wt_m2, *wt_k, *wt_v, *wt_ae, *q_all;
  float *mem_ctx;
};

__device__ __forceinline__ bfrag mk_afrag(const float* xr, int kc, int qd) {
  const float* s = xr + kc * 32 + qd * 8;
  float4 a = *(const float4*)s;
  float4 b = *(const float4*)(s + 4);
  short t[8] = {f2bf(a.x), f2bf(a.y), f2bf(a.z), f2bf(a.w),
                f2bf(b.x), f2bf(b.y), f2bf(b.z), f2bf(b.w)};
  return *(bfrag*)t;
}

__global__ __launch_bounds__(1024, 4) void scan2_k(Scan2Params p) {
  const int tid = threadIdx.x;
  const int lane = tid & 63, w = tid >> 6;     // wave 0..15
  const int bb = w >> 3, h = w & 7;            // this wave's (local b, head)
  const int l15 = lane & 15, qd = lane >> 4;
  const int b0 = blockIdx.x * 2;

  __shared__ float xcat[2][1024];   // [us_norm | mem_ctx]
  __shared__ float rbuf[2][512];
  __shared__ float x2b[2][512];
  __shared__ float mo[2][1040];
  __shared__ float modv[2][512];
  __shared__ float kvb[2][1024];    // [k | v]
  __shared__ float khat[16][64];
  __shared__ float qh[16][64];
  __shared__ float aeta[2][8][2];   // [b][h][{alpha,eta}]
  __shared__ float st[2][2], st2[2][2];
  __shared__ float cb1[512], cg[512], cbt[512], cb2[1040];
  __shared__ float cn1g[512], cn1b[512], cba[8], cbe[8];

  // preload per-block constants + us_norm
  if (tid < 512) {
    cb1[tid] = p.mcb1[tid]; cg[tid] = p.mcg[tid]; cbt[tid] = p.mcbt[tid];
    cn1g[tid] = p.n1g[tid]; cn1b[tid] = p.n1b[tid];
  }
  cb2[tid] = p.mcb2[tid];
  if (tid < 16) cb2[1024 + tid] = p.mcb2[1024 + tid];
  if (tid < 8) { cba[tid] = p.ba[tid]; cbe[tid] = p.be[tid]; }
  {
    int row = tid >> 9, c = tid & 511;
    xcat[row][c] = p.us_norm[(size_t)(b0 + row) * cD + c];
  }

  // load persistent state into registers
  float S[64];
  {
    const float* sp = p.init_state + ((((size_t)(b0 + bb)) * cH + h) * cDH + lane) * cDH;
#pragma unroll
    for (int j = 0; j < 64; j += 4) {
      float4 t4 = *(const float4*)(sp + j);
      S[j] = t4.x; S[j + 1] = t4.y; S[j + 2] = t4.z; S[j + 3] = t4.w;
    }
  }
  float memv;
  {  // mem_ctx_0 = S . q̂_0
    float qv = bf2f(p.q_all[(size_t)(b0 + bb) * cD + h * cDH + lane]);
    float qs = qv * qv;
#pragma unroll
    for (int o = 32; o >= 1; o >>= 1) qs += __shfl_xor(qs, o);
    qh[w][lane] = qv / fmaxf(sqrtf(qs), 1e-12f);
    memv = 0.f;
#pragma unroll
    for (int j = 0; j < 64; j += 4) {
      float4 q4 = *(const float4*)&qh[w][j];
      memv += S[j] * q4.x + S[j + 1] * q4.y + S[j + 2] * q4.z + S[j + 3] * q4.w;
    }
    xcat[bb][512 + h * cDH + lane] = memv;
  }
  __syncthreads();

  for (int t = 0; t < cT; ++t) {
    // ---- P1: r = xcat @ mcW1 + b1 (32 col-tiles; 2 per wave) ----
    {
      f32x4 a0 = {}, a1 = {};
      const int n0 = w * 16, n1 = (w + 16) * 16;
#pragma unroll 4
      for (int kc = 0; kc < 32; ++kc) {
        bfrag A = {};
        if (l15 < 2) A = mk_afrag(&xcat[l15][0], kc, qd);
        bfrag B0 = *(const bfrag*)(p.wt_m1 + (size_t)(n0 + l15) * 1024 + kc * 32 + qd * 8);
        bfrag B1 = *(const bfrag*)(p.wt_m1 + (size_t)(n1 + l15) * 1024 + kc * 32 + qd * 8);
        a0 = __builtin_amdgcn_mfma_f32_16x16x32_bf16(A, B0, a0, 0, 0, 0);
        a1 = __builtin_amdgcn_mfma_f32_16x16x32_bf16(A, B1, a1, 0, 0, 0);
      }
      if (lane < 16) {  // C rows 0,1 = regs 0,1 of quad 0
        rbuf[0][n0 + lane] = a0[0] + cb1[n0 + lane];
        rbuf[1][n0 + lane] = a0[1] + cb1[n0 + lane];
        rbuf[0][n1 + lane] = a1[0] + cb1[n1 + lane];
        rbuf[1][n1 + lane] = a1[1] + cb1[n1 + lane];
      }
    }
    __syncthreads();
    // ---- P2: LN stats of r (waves 0,1); wave 2 loads item LN stats ----
    if (w < 2) {
      float s = 0.f, ss = 0.f;
#pragma unroll
      for (int i = 0; i < 8; ++i) { float v = rbuf[w][lane + i * 64]; s += v; ss += v * v; }
#pragma unroll
      for (int o = 32; o >= 1; o >>= 1) { s += __shfl_xor(s, o); ss += __shfl_xor(ss, o); }
      if (lane == 0) {
        float m = s * (1.f / cD);
        st[w][0] = m;
        st[w][1] = rsqrtf(ss * (1.f / cD) - m * m + 1e-5f);
      }
    } else if (w == 2 && lane < 2) {
      st2[lane][0] = p.lnm[t * cB + b0 + lane];
      st2[lane][1] = p.lnr[t * cB + b0 + lane];
    }
    __syncthreads();
    // ---- P3: x2 = relu(LN(r)) ----
    {
      int row = tid >> 9, c = tid & 511;
      x2b[row][c] = fmaxf((rbuf[row][c] - st[row][0]) * st[row][1] * cg[c] + cbt[c], 0.f);
    }
    __syncthreads();
    // ---- P4: mo = x2 @ mcW2 + b2 (65 tiles: 4/wave + tile 64 by wave 0) ----
    {
      f32x4 acc[4] = {};
#pragma unroll 2
      for (int kc = 0; kc < 16; ++kc) {
        bfrag A = {};
        if (l15 < 2) A = mk_afrag(&x2b[l15][0], kc, qd);
#pragma unroll
        for (int tI = 0; tI < 4; ++tI) {
          int n0 = (tI * 16 + w) * 16;
          bfrag B = *(const bfrag*)(p.wt_m2 + (size_t)(n0 + l15) * 512 + kc * 32 + qd * 8);
          acc[tI] = __builtin_amdgcn_mfma_f32_16x16x32_bf16(A, B, acc[tI], 0, 0, 0);
        }
      }
      if (lane < 16)
#pragma unroll
        for (int tI = 0; tI < 4; ++tI) {
          int n0 = (tI * 16 + w) * 16;
          mo[0][n0 + lane] = acc[tI][0] + cb2[n0 + lane];
          mo[1][n0 + lane] = acc[tI][1] + cb2[n0 + lane];
        }
      if (w == 0) {  // tile 64: cols 1024..1039 (alpha/eta biases)
        f32x4 e = {};
        for (int kc = 0; kc < 16; ++kc) {
          bfrag A = {};
          if (l15 < 2) A = mk_afrag(&x2b[l15][0], kc, qd);
          bfrag B = *(const bfrag*)(p.wt_m2 + (size_t)(1024 + l15) * 512 + kc * 32 + qd * 8);
          e = __builtin_amdgcn_mfma_f32_16x16x32_bf16(A, B, e, 0, 0, 0);
        }
        if (lane < 16) {
          mo[0][1024 + lane] = e[0] + cb2[1024 + lane];
          mo[1][1024 + lane] = e[1] + cb2[1024 + lane];
        }
      }
    }
    __syncthreads();
    // ---- P5: mod = i_norm*(1+tanh(gamma)) + beta ----
    {
      int row = tid >> 9, c = tid & 511;
      float inm = (p.item_seq[(((size_t)(b0 + row)) * cT + t) * cD + c] - st2[row][0]) *
                      st2[row][1] * cn1g[c] + cn1b[c];
      modv[row][c] = inm * (1.f + tanhf(mo[row][c])) + mo[row][512 + c];
    }
    __syncthreads();
    // ---- P6: [k|v] = mod @ [Wk|Wv]; alpha/eta tile by wave 0 ----
    {
      f32x4 acc[4] = {};
#pragma unroll 2
      for (int kc = 0; kc < 16; ++kc) {
        bfrag A = {};
        if (l15 < 2) A = mk_afrag(&modv[l15][0], kc, qd);
#pragma unroll
        for (int tI = 0; tI < 4; ++tI) {
          int tile = tI * 16 + w;
          const short* wt = (tile < 32) ? p.wt_k : p.wt_v;
          int n0 = ((tile < 32) ? tile : tile - 32) * 16;
          bfrag B = *(const bfrag*)(wt + (size_t)(n0 + l15) * 512 + kc * 32 + qd * 8);
          acc[tI] = __builtin_amdgcn_mfma_f32_16x16x32_bf16(A, B, acc[tI], 0, 0, 0);
        }
      }
      if (lane < 16)
#pragma unroll
        for (int tI = 0; tI < 4; ++tI) {
          int tile = tI * 16 + w;
          int dst = (tile < 32) ? tile * 16 + lane : 512 + (tile - 32) * 16 + lane;
          kvb[0][dst] = acc[tI][0];
          kvb[1][dst] = acc[tI][1];
        }
      if (w == 0) {  // [Wa|We] 16-col tile -> alpha, eta
        f32x4 e = {};
        for (int kc = 0; kc < 16; ++kc) {
          bfrag A = {};
          if (l15 < 2) A = mk_afrag(&modv[l15][0], kc, qd);
          bfrag B = *(const bfrag*)(p.wt_ae + (size_t)l15 * 512 + kc * 32 + qd * 8);
          e = __builtin_amdgcn_mfma_f32_16x16x32_bf16(A, B, e, 0, 0, 0);
        }
        if (lane < 16) {
          if (lane < 8) {
            int hh = lane;
            aeta[0][hh][0] = sigm(e[0] + cba[hh] + mo[0][1024 + hh]);
            aeta[1][hh][0] = sigm(e[1] + cba[hh] + mo[1][1024 + hh]);
          } else {
            int hh = lane - 8;
            aeta[0][hh][1] = cSCALE * sigm(e[0] + cbe[hh] + mo[0][1032 + hh]);
            aeta[1][hh][1] = cSCALE * sigm(e[1] + cbe[hh] + mo[1][1032 + hh]);
          }
        }
      }
    }
    __syncthreads();
    // ---- P7: state update (registers) + mem with q_{t+1} ----
    {
      float kvv = kvb[bb][h * cDH + lane];
      float ks = kvv * kvv;
#pragma unroll
      for (int o = 32; o >= 1; o >>= 1) ks += __shfl_xor(ks, o);
      khat[w][lane] = kvv / fmaxf(sqrtf(ks), 1e-12f);
      float qv = bf2f(p.q_all[((size_t)(t + 1) * cB + (b0 + bb)) * cD + h * cDH + lane]);
      float qs = qv * qv;
#pragma unroll
      for (int o = 32; o >= 1; o >>= 1) qs += __shfl_xor(qs, o);
      qh[w][lane] = qv / fmaxf(sqrtf(qs), 1e-12f);

      float vv = kvb[bb][512 + h * cDH + lane];
      float al = aeta[bb][h][0], et = aeta[bb][h][1];
      float pred = 0.f;
#pragma unroll
      for (int j = 0; j < 64; j += 4) {
        float4 k4 = *(const float4*)&khat[w][j];
        pred += S[j] * k4.x + S[j + 1] * k4.y + S[j + 2] * k4.z + S[j + 3] * k4.w;
      }
      float f = et * (vv - pred), oma = 1.f - al;
      memv = 0.f;
#pragma unroll
      for (int j = 0; j < 64; j += 4) {
        float4 k4 = *(const float4*)&khat[w][j];
        float4 q4 = *(const float4*)&qh[w][j];
        S[j]     = oma * S[j]     + f * k4.x; memv += S[j]     * q4.x;
        S[j + 1] = oma * S[j + 1] + f * k4.y; memv += S[j + 1] * q4.y;
        S[j + 2] = oma * S[j + 2] + f * k4.z; memv += S[j + 2] * q4.z;
        S[j + 3] = oma * S[j + 3] + f * k4.w; memv += S[j + 3] * q4.w;
      }
      xcat[bb][512 + h * cDH + lane] = memv;
    }
    __syncthreads();
  }

  // final memory read (slot 64 = last-item query) is in memv
  p.mem_ctx[(size_t)(b0 + bb) * cD + h * cDH + lane] = memv;
}

// ======================= host launch ========================================
extern "C" void kernel_launch(void* const* d_in, const int* in_sizes, int n_in,
                              void* d_out, int out_size, void* d_ws, size_t ws_size,
                              hipStream_t stream) {
  (void)in_sizes; (void)n_in; (void)out_size;
  const float* item_seq   = (const float*)d_in[0];
  const float* user_stat  = (const float*)d_in[1];
  const float* last_item  = (const float*)d_in[2];
  const float* init_state = (const float*)d_in[3];
  const float* Wq  = (const float*)d_in[4];
  const float* Wk  = (const float*)d_in[5];
  const float* Wv  = (const float*)d_in[6];
  const float* Wa  = (const float*)d_in[7];
  const float* ba  = (const float*)d_in[8];
  const float* We  = (const float*)d_in[9];
  const float* be  = (const float*)d_in[10];
  const float* mcW1 = (const float*)d_in[11];
  const float* mcb1 = (const float*)d_in[12];
  const float* mcg  = (const float*)d_in[13];
  const float* mcbt = (const float*)d_in[14];
  const float* mcW2 = (const float*)d_in[15];
  const float* mcb2 = (const float*)d_in[16];
  const float* Wo  = (const float*)d_in[17];
  const float* bo  = (const float*)d_in[18];
  const float* W1  = (const float*)d_in[19];
  const float* b1  = (const float*)d_in[20];
  const float* W2  = (const float*)d_in[21];
  const float* b2  = (const float*)d_in[22];
  const float* n1g = (const float*)d_in[23];
  const float* n1b = (const float*)d_in[24];
  const float* n2g = (const float*)d_in[25];
  const float* n2b = (const float*)d_in[26];

  float* ws = (float*)d_ws;
  size_t off = 0;
  auto alloc = [&](size_t n) { float* p = ws + off; off += n; return p; };
  auto salloc = [&](size_t n) { return (short*)alloc((n + 1) / 2); };

  short* q_all   = salloc((size_t)(cT + 1) * cB * cD);
  float* lnm     = alloc((size_t)(cT + 1) * cB);
  float* lnr     = alloc((size_t)(cT + 1) * cB);
  float* us_norm = alloc((size_t)cB * cD);
  float* mem_ctx = alloc((size_t)cB * cD);
  float* x_buf   = alloc((size_t)cB * cD);
  float* xm      = alloc(cB);
  float* xr      = alloc(cB);
  float* u_buf   = alloc((size_t)cB * cFF);
  short* wt_q    = salloc((size_t)512 * 512);
  short* wt_m1   = salloc((size_t)512 * 1024);
  short* wt_m2   = salloc((size_t)1040 * 512);
  short* wt_k    = salloc((size_t)512 * 512);
  short* wt_v    = salloc((size_t)512 * 512);
  short* wt_ae   = salloc((size_t)16 * 512);
  short* wt_o    = salloc((size_t)512 * 512);
  short* wt_o_l  = salloc((size_t)512 * 512);
  short* wt_1    = salloc((size_t)2048 * 512);
  short* wt_1_l  = salloc((size_t)2048 * 512);
  short* wt_2    = salloc((size_t)512 * 2048);
  short* wt_2_l  = salloc((size_t)512 * 2048);
  if (ws_size < off * sizeof(float)) return;

  // --- prep: bf16 transposed weights ---
  tconv<<<dim3(16, 16), 256, 0, stream>>>(Wq, wt_q, 512, 512);
  tconv<<<dim3(32, 16), 256, 0, stream>>>(mcW1, wt_m1, 1024, 512);
  tconv<<<dim3(16, 33), 256, 0, stream>>>(mcW2, wt_m2, 512, 1040);
  tconv<<<dim3(16, 16), 256, 0, stream>>>(Wk, wt_k, 512, 512);
  tconv<<<dim3(16, 16), 256, 0, stream>>>(Wv, wt_v, 512, 512);
  tconv<<<dim3(16, 1), 256, 0, stream>>>(Wa, wt_ae, 512, 8);
  tconv<<<dim3(16, 1), 256, 0, stream>>>(We, wt_ae + (size_t)8 * 512, 512, 8);
  tconv2<<<dim3(16, 16), 256, 0, stream>>>(Wo, wt_o, wt_o_l, 512, 512);
  tconv2<<<dim3(16, 64), 256, 0, stream>>>(W1, wt_1, wt_1_l, 512, 2048);
  tconv2<<<dim3(64, 16), 256, 0, stream>>>(W2, wt_2, wt_2_l, 2048, 512);

  ln_stats_k<<<(cT * cB + 2 * cB) / 4, 256, 0, stream>>>(
      item_seq, last_item, user_stat, n1g, n1b, lnm, lnr, us_norm);

  {  // q_all for all 65 slots (bf16 out)
    GemmArgs p{}; p.A = item_seq; p.A2 = last_item; p.sm = lnm; p.sr = lnr;
    p.g = n1g; p.b = n1b; p.WT = wt_q; p.Os = q_all;
    mgemm<MQ, 512><<<dim3(520, 8), 256, 0, stream>>>(p, 512);
  }

  {  // --- barrier-free scan: one block per 2 batch rows ---
    Scan2Params sp{};
    sp.item_seq = item_seq; sp.init_state = init_state; sp.us_norm = us_norm;
    sp.lnm = lnm; sp.lnr = lnr; sp.n1g = n1g; sp.n1b = n1b;
    sp.mcb1 = mcb1; sp.mcg = mcg; sp.mcbt = mcbt; sp.mcb2 = mcb2;
    sp.ba = ba; sp.be = be;
    sp.wt_m1 = wt_m1; sp.wt_m2 = wt_m2; sp.wt_k = wt_k; sp.wt_v = wt_v;
    sp.wt_ae = wt_ae; sp.q_all = q_all;
    sp.mem_ctx = mem_ctx;
    scan2_k<<<dim3(cB / 2), dim3(1024), 0, stream>>>(sp);
  }

  {  // x = user + mem_ctx @ Wo + bo  (split precision)
    GemmArgs p{}; p.A = mem_ctx; p.WT = wt_o; p.WT2 = wt_o_l;
    p.bias = bo; p.extra = user_stat; p.O = x_buf;
    pgemm<MWO, 512><<<dim3(8, 8), 256, 0, stream>>>(p, 512);
  }
  row_stats_k<<<cB / 4, 256, 0, stream>>>(x_buf, xm, xr);
  {  // u = relu(LN(x) @ W1 + b1)  (split precision)
    GemmArgs p{}; p.A = x_buf; p.sm = xm; p.sr = xr; p.g = n2g; p.b = n2b;
    p.WT = wt_1; p.WT2 = wt_1_l; p.bias = b1; p.O = u_buf;
    pgemm<MFF1, 512><<<dim3(8, 32), 256, 0, stream>>>(p, 512);
  }
  {  // out = x + u @ W2 + b2  (split precision)
    GemmArgs p{}; p.A = u_buf; p.WT = wt_2; p.WT2 = wt_2_l;
    p.bias = b2; p.extra = x_buf; p.O = (float*)d_out;
    pgemm<MFF2, 2048><<<dim3(8, 8), 256, 0, stream>>>(p, 2048);
  }
}